// Round 4
// baseline (2144.397 us; speedup 1.0000x reference)
//
#include <hip/hip_runtime.h>
#include <hip/hip_bf16.h>

typedef __bf16 bf16_t;
typedef __attribute__((ext_vector_type(8))) __bf16 bf16x8;
typedef __attribute__((ext_vector_type(16))) float f32x16;

#define B_ 8
#define T_ 16
#define C_ 8
#define F_ 32
#define H_ 128
#define W_ 128
#define HO 126
#define WO 126
#define NKK 23
#define NBLK 256

#define BQ (NKK * 4096)              // 94208 B: B panels, [kk][nt][lane][16B]
#define XS_OFF BQ                    // x_s [34][18][8c] bf16, row stride 288 B
#define HS_OFF (BQ + 9792)           // h_s [4fg][34][18][8f], fg stride 9792 B
#define LDS_BYTES (BQ + 9792 + 39168)   // 143168 B -> 1 block/CU

// -------- B prepack (verified R2): Bp[kk][nt][lane][j] bf16 --------
__global__ __launch_bounds__(256) void prep_B(const float* __restrict__ Wk,
                                              const float* __restrict__ Uk,
                                              bf16_t* __restrict__ Bp) {
    int e = blockIdx.x * 256 + threadIdx.x;   // grid = 23*2048 exactly
    int j = e & 7, lane = (e >> 3) & 63, nt = (e >> 9) & 3, kk = e >> 11;
    int n = nt * 32 + (lane & 31), half = lane >> 5;
    float v = 0.f;
    if (kk < 5) {
        int p = 2 * kk + half, c = j;
        if (p <= 8) v = Wk[((n * C_ + c) * 3 + p / 3) * 3 + (p % 3)];
    } else {
        int kk2 = kk - 5, q = kk2 >> 1;
        int f = ((kk2 & 1) << 4) + (half << 3) + j;
        v = Uk[((n * F_ + f) * 3 + q / 3) * 3 + (q % 3)];
    }
    Bp[e] = (bf16_t)v;
}

// -------- x: NCHW fp32 -> [b][t][y][x][8c] bf16 --------
__global__ __launch_bounds__(128) void conv_x(const float* __restrict__ x,
                                              bf16_t* __restrict__ xb) {
    const int tx = threadIdx.x;
    const int y = blockIdx.x, tb = blockIdx.y, bb = blockIdx.z;
    const float* xp = x + ((size_t)(bb * T_ + tb) * C_) * (H_ * W_) + y * W_ + tx;
    bf16x8 v;
    #pragma unroll
    for (int c = 0; c < 8; ++c) v[c] = (bf16_t)xp[(size_t)c * (H_ * W_)];
    *(bf16x8*)(xb + (((size_t)(bb * T_ + tb) * H_ + y) * W_ + tx) * 8) = v;
}

// -------- multi-step ConvLSTM; nsteps>1 requires cooperative launch --------
__global__ __launch_bounds__(512, 2) void lstm_persist(
    const bf16_t* __restrict__ xb,
    const bf16_t* __restrict__ Bp,
    const float* __restrict__ bias,
    bf16_t* __restrict__ h0,
    bf16_t* __restrict__ h1,
    float* __restrict__ cbuf,   // fp32 NHWC c state (global round-trip)
    int* __restrict__ bar,
    int t0, int nsteps)
{
    __shared__ __align__(16) unsigned char smem[LDS_BYTES];
    const int tid = threadIdx.x;
    const int w = tid >> 6, l = tid & 63;
    const int half = l >> 5;
    const int bid = blockIdx.x;
    const int bx = bid & 7, by = (bid >> 3) & 3, bb = bid >> 5;
    const int r0 = by * 32, c0 = bx * 16;

    // load all B panels into LDS once per dispatch
    for (int i = tid; i < BQ / 16; i += 512)
        *(bf16x8*)(smem + i * 16) = *(const bf16x8*)(Bp + i * 8);

    const int fch = l & 31;
    float bv[4];
    #pragma unroll
    for (int n = 0; n < 4; ++n) bv[n] = bias[n * 32 + fch];

    const int trA = w * 4 + ((l & 31) >> 4);
    const int tcA = l & 15;
    const int baseX0 = XS_OFF + trA * 288 + tcA * 16;                 // m=0 (+576 m=1)
    const int baseH0 = HS_OFF + half * 9792 + trA * 288 + tcA * 16;

    // ---- c state: load from global ----
    float* cbp = cbuf + (size_t)bb * (HO * WO * F_);
    float cre[2][16];
    #pragma unroll
    for (int m = 0; m < 2; ++m)
        #pragma unroll
        for (int r = 0; r < 16; ++r) {
            const int row = (r & 3) + ((r >> 2) << 3) + (half << 2);
            const int px = w * 64 + m * 32 + row;
            const int gy = r0 + (px >> 4), gx = c0 + (px & 15);
            cre[m][r] = (gy < HO && gx < WO) ? cbp[((size_t)gy * WO + gx) * F_ + fch] : 0.f;
        }

    constexpr int OFFT[10] = {0, 16, 32, 288, 304, 320, 576, 592, 608, 864};

    #pragma unroll 1
    for (int ts = 0; ts < nsteps; ++ts) {
        const int t = t0 + ts;
        const bf16_t* hr = (t & 1) ? h1 : h0;
        bf16_t* hw = (t & 1) ? h0 : h1;

        // ---- stage x tile: rows r0..r0+33, cols c0..c0+17 ----
        const bf16_t* xt = xb + (size_t)(bb * T_ + t) * (H_ * W_ * 8);
        for (int i = tid; i < 612; i += 512) {
            int row = i / 18, col = i % 18;
            int gy = r0 + row, gx = c0 + col;
            bf16x8 v = {};
            if (gy < H_ && gx < W_) v = *(const bf16x8*)(xt + ((size_t)gy * W_ + gx) * 8);
            *(bf16x8*)(smem + XS_OFF + row * 288 + col * 16) = v;
        }
        // ---- stage h tile (SAME pad): rows r0-1..r0+32, cols c0-1..c0+16 ----
        const bf16_t* hbR = hr + (size_t)bb * (HO * WO * F_);
        for (int i = tid; i < 2448; i += 512) {
            int pix = i >> 2, fg = i & 3;
            int row = pix / 18, col = pix % 18;
            int gy = r0 - 1 + row, gx = c0 - 1 + col;
            bf16x8 v = {};
            if (gy >= 0 && gy < HO && gx >= 0 && gx < WO)
                v = *(const bf16x8*)(hbR + ((size_t)gy * WO + gx) * F_ + fg * 8);
            *(bf16x8*)(smem + HS_OFF + fg * 9792 + row * 288 + col * 16) = v;
        }
        __syncthreads();

        f32x16 acc[2][4];
        #pragma unroll
        for (int m = 0; m < 2; ++m)
            #pragma unroll
            for (int n = 0; n < 4; ++n)
                #pragma unroll
                for (int j = 0; j < 16; ++j) acc[m][n][j] = bv[n];

        // ---- barrier-free K-loop: 23 k16-steps, 6 ds_read_b128 + 8 MFMA each ----
        #pragma unroll
        for (int kk = 0; kk < NKK; ++kk) {
            int base0;
            if (kk < 5) {
                // tap p = 2kk+half; p==9 reads past x_s (finite garbage x zero-B, in-bounds)
                base0 = baseX0 + (half ? OFFT[2 * kk + 1] : OFFT[2 * kk]);
            } else {
                const int kk2 = kk - 5, q = kk2 >> 1, fgrp = kk2 & 1;
                base0 = baseH0 + fgrp * 19584 + (q / 3) * 288 + (q % 3) * 16;
            }
            bf16x8 a0 = *(const bf16x8*)(smem + base0);
            bf16x8 a1 = *(const bf16x8*)(smem + base0 + 576);   // m=1: +2 rows
            const int bbo = kk * 4096 + l * 16;
            bf16x8 b0 = *(const bf16x8*)(smem + bbo);
            bf16x8 b1 = *(const bf16x8*)(smem + bbo + 1024);
            bf16x8 b2 = *(const bf16x8*)(smem + bbo + 2048);
            bf16x8 b3 = *(const bf16x8*)(smem + bbo + 3072);
            acc[0][0] = __builtin_amdgcn_mfma_f32_32x32x16_bf16(a0, b0, acc[0][0], 0, 0, 0);
            acc[0][1] = __builtin_amdgcn_mfma_f32_32x32x16_bf16(a0, b1, acc[0][1], 0, 0, 0);
            acc[0][2] = __builtin_amdgcn_mfma_f32_32x32x16_bf16(a0, b2, acc[0][2], 0, 0, 0);
            acc[0][3] = __builtin_amdgcn_mfma_f32_32x32x16_bf16(a0, b3, acc[0][3], 0, 0, 0);
            acc[1][0] = __builtin_amdgcn_mfma_f32_32x32x16_bf16(a1, b0, acc[1][0], 0, 0, 0);
            acc[1][1] = __builtin_amdgcn_mfma_f32_32x32x16_bf16(a1, b1, acc[1][1], 0, 0, 0);
            acc[1][2] = __builtin_amdgcn_mfma_f32_32x32x16_bf16(a1, b2, acc[1][2], 0, 0, 0);
            acc[1][3] = __builtin_amdgcn_mfma_f32_32x32x16_bf16(a1, b3, acc[1][3], 0, 0, 0);
        }

        // ---- fused LSTM epilogue: c in registers, h -> global bf16 NHWC ----
        bf16_t* hwb = hw + (size_t)bb * (HO * WO * F_);
        #pragma unroll
        for (int m = 0; m < 2; ++m)
            #pragma unroll
            for (int r = 0; r < 16; ++r) {
                const int row = (r & 3) + ((r >> 2) << 3) + (half << 2);
                const int px = w * 64 + m * 32 + row;
                const int gy = r0 + (px >> 4), gx = c0 + (px & 15);
                float zi = acc[m][0][r], zf = acc[m][1][r], zg = acc[m][2][r], zo = acc[m][3][r];
                float ig = fminf(fmaxf(0.2f * zi + 0.5f, 0.f), 1.f);
                float fg = fminf(fmaxf(0.2f * zf + 0.5f, 0.f), 1.f);
                float og = fminf(fmaxf(0.2f * zo + 0.5f, 0.f), 1.f);
                float eg = __expf(2.f * zg);
                float tg = 1.f - 2.f / (eg + 1.f);
                float cn = fg * cre[m][r] + ig * tg;
                cre[m][r] = cn;
                float ec = __expf(2.f * cn);
                float hn = og * (1.f - 2.f / (ec + 1.f));
                if (gy < HO && gx < WO)
                    hwb[((size_t)gy * WO + gx) * F_ + fch] = (bf16_t)hn;
            }

        // ---- grid barrier (only between in-kernel steps; bounded spin) ----
        if (ts < nsteps - 1) {
            __threadfence();                 // release h stores (all threads)
            __syncthreads();
            if (tid == 0) {
                atomicAdd(&bar[t], 1);       // device-scope by default
                int it = 0;
                while (__hip_atomic_load(&bar[t], __ATOMIC_ACQUIRE,
                                         __HIP_MEMORY_SCOPE_AGENT) < NBLK &&
                       it < (1 << 13)) {
                    __builtin_amdgcn_s_sleep(4);
                    ++it;
                }
            }
            __syncthreads();
            __threadfence();                 // acquire: drop stale cached h lines
        }
    }

    // ---- c state: store to global ----
    #pragma unroll
    for (int m = 0; m < 2; ++m)
        #pragma unroll
        for (int r = 0; r < 16; ++r) {
            const int row = (r & 3) + ((r >> 2) << 3) + (half << 2);
            const int px = w * 64 + m * 32 + row;
            const int gy = r0 + (px >> 4), gx = c0 + (px & 15);
            if (gy < HO && gx < WO)
                cbp[((size_t)gy * WO + gx) * F_ + fch] = cre[m][r];
        }
}

// -------- final h: NHWC bf16 -> NCHW fp32 --------
__global__ __launch_bounds__(256) void out_transpose(const bf16_t* __restrict__ h,
                                                     float* __restrict__ out) {
    __shared__ float tile[WO * 33];
    const int gy = blockIdx.x, bb = blockIdx.y;
    const bf16_t* hp = h + ((size_t)bb * HO + gy) * (WO * F_);
    for (int i = threadIdx.x; i < WO * F_; i += 256) {
        int gx = i >> 5, f = i & 31;
        tile[gx * 33 + f] = (float)hp[i];
    }
    __syncthreads();
    float* op = out + (size_t)bb * (F_ * HO * WO) + (size_t)gy * WO;
    for (int i = threadIdx.x; i < WO * F_; i += 256) {
        int f = i / WO, gx = i % WO;
        op[(size_t)f * (HO * WO) + gx] = tile[gx * 33 + f];
    }
}

extern "C" void kernel_launch(void* const* d_in, const int* in_sizes, int n_in,
                              void* d_out, int out_size, void* d_ws, size_t ws_size,
                              hipStream_t stream) {
    const float* x    = (const float*)d_in[0];
    const float* Wk   = (const float*)d_in[1];
    const float* Uk   = (const float*)d_in[2];
    const float* bias = (const float*)d_in[3];
    float* out = (float*)d_out;

    const size_t N = (size_t)B_ * HO * WO * F_;    // 4,064,256 state elems
    bf16_t* h0p  = (bf16_t*)d_ws;
    bf16_t* h1p  = h0p + N;
    bf16_t* Bp   = h1p + N;                         // 47,104 bf16
    bf16_t* xbuf = Bp + 47104;                      // 16,777,216 bf16
    float*  cbuf = (float*)(xbuf + (size_t)16777216);
    int*    bar  = (int*)(cbuf + N);                // 16 ints; total ~66.2 MB

    conv_x<<<dim3(H_, T_, B_), 128, 0, stream>>>(x, xbuf);
    prep_B<<<184, 256, 0, stream>>>(Wk, Uk, Bp);
    hipMemsetAsync(h0p, 0, N * sizeof(bf16_t), stream);
    hipMemsetAsync(cbuf, 0, N * sizeof(float), stream);
    hipMemsetAsync(bar, 0, 16 * sizeof(int), stream);

    int t0 = 0, ns = T_;
    const bf16_t* xbc = xbuf;
    const bf16_t* Bpc = Bp;
    void* args[] = {(void*)&xbc, (void*)&Bpc, (void*)&bias, (void*)&h0p,
                    (void*)&h1p, (void*)&cbuf, (void*)&bar, (void*)&t0, (void*)&ns};
    hipError_t ce = hipLaunchCooperativeKernel((const void*)lstm_persist,
                                               dim3(NBLK), dim3(512), args, 0, stream);
    if (ce != hipSuccess) {
        // fallback: 16 plain single-step launches (no in-kernel barrier runs)
        for (int t = 0; t < T_; ++t)
            lstm_persist<<<NBLK, 512, 0, stream>>>(xbuf, Bp, bias, h0p, h1p,
                                                   cbuf, bar, t, 1);
    }

    // t=15 (odd) wrote h0
    out_transpose<<<dim3(HO, B_), 256, 0, stream>>>(h0p, out);
}

// Round 5
// 1295.562 us; speedup vs baseline: 1.6552x; 1.6552x over previous
//
#include <hip/hip_runtime.h>
#include <hip/hip_bf16.h>

typedef __bf16 bf16_t;
typedef __attribute__((ext_vector_type(8))) __bf16 bf16x8;
typedef __attribute__((ext_vector_type(16))) float f32x16;

#define B_ 8
#define T_ 16
#define C_ 8
#define F_ 32
#define H_ 128
#define W_ 128
#define HO 126
#define WO 126
#define NKK 23
#define NBLK 256

#define BQ (NKK * 4096)              // 94208 B: B panels, [kk][nt][lane][16B]
#define XS_OFF BQ                    // x_s [34][18][8c] bf16, row stride 288 B
#define HS_OFF (BQ + 9792)           // h_s [4fg][34][18][8f], fg stride 9792 B
#define LDS_BYTES (BQ + 9792 + 39168)   // 143168 B -> 1 block/CU

// -------- B prepack (verified R2): Bp[kk][nt][lane][j] bf16 --------
__global__ __launch_bounds__(256) void prep_B(const float* __restrict__ Wk,
                                              const float* __restrict__ Uk,
                                              bf16_t* __restrict__ Bp) {
    int e = blockIdx.x * 256 + threadIdx.x;   // grid = 23*2048 exactly
    int j = e & 7, lane = (e >> 3) & 63, nt = (e >> 9) & 3, kk = e >> 11;
    int n = nt * 32 + (lane & 31), half = lane >> 5;
    float v = 0.f;
    if (kk < 5) {
        int p = 2 * kk + half, c = j;
        if (p <= 8) v = Wk[((n * C_ + c) * 3 + p / 3) * 3 + (p % 3)];
    } else {
        int kk2 = kk - 5, q = kk2 >> 1;
        int f = ((kk2 & 1) << 4) + (half << 3) + j;
        v = Uk[((n * F_ + f) * 3 + q / 3) * 3 + (q % 3)];
    }
    Bp[e] = (bf16_t)v;
}

// -------- x: NCHW fp32 -> [b][t][y][x][8c] bf16 --------
__global__ __launch_bounds__(128) void conv_x(const float* __restrict__ x,
                                              bf16_t* __restrict__ xb) {
    const int tx = threadIdx.x;
    const int y = blockIdx.x, tb = blockIdx.y, bb = blockIdx.z;
    const float* xp = x + ((size_t)(bb * T_ + tb) * C_) * (H_ * W_) + y * W_ + tx;
    bf16x8 v;
    #pragma unroll
    for (int c = 0; c < 8; ++c) v[c] = (bf16_t)xp[(size_t)c * (H_ * W_)];
    *(bf16x8*)(xb + (((size_t)(bb * T_ + tb) * H_ + y) * W_ + tx) * 8) = v;
}

// -------- multi-step ConvLSTM; nsteps>1 requires cooperative launch --------
__global__ __launch_bounds__(512, 2) void lstm_persist(
    const bf16_t* __restrict__ xb,
    const bf16_t* __restrict__ Bp,
    const float* __restrict__ bias,
    bf16_t* __restrict__ h0,
    bf16_t* __restrict__ h1,
    float* __restrict__ cbuf,   // fp32 NHWC c state (global round-trip)
    int* __restrict__ bar,
    int t0, int nsteps)
{
    __shared__ __align__(16) unsigned char smem[LDS_BYTES];
    const int tid = threadIdx.x;
    const int w = tid >> 6, l = tid & 63;
    const int half = l >> 5;
    const int bid = blockIdx.x;
    const int bx = bid & 7, by = (bid >> 3) & 3, bb = bid >> 5;
    const int r0 = by * 32, c0 = bx * 16;

    // load all B panels into LDS once per dispatch
    for (int i = tid; i < BQ / 16; i += 512)
        *(bf16x8*)(smem + i * 16) = *(const bf16x8*)(Bp + i * 8);

    const int fch = l & 31;
    float bv[4];
    #pragma unroll
    for (int n = 0; n < 4; ++n) bv[n] = bias[n * 32 + fch];

    const int trA = w * 4 + ((l & 31) >> 4);
    const int tcA = l & 15;
    const int baseX0 = XS_OFF + trA * 288 + tcA * 16;                 // m=0 (+576 m=1)
    const int baseH0 = HS_OFF + half * 9792 + trA * 288 + tcA * 16;

    // ---- c state: load from global ----
    float* cbp = cbuf + (size_t)bb * (HO * WO * F_);
    float cre[2][16];
    #pragma unroll
    for (int m = 0; m < 2; ++m)
        #pragma unroll
        for (int r = 0; r < 16; ++r) {
            const int row = (r & 3) + ((r >> 2) << 3) + (half << 2);
            const int px = w * 64 + m * 32 + row;
            const int gy = r0 + (px >> 4), gx = c0 + (px & 15);
            cre[m][r] = (gy < HO && gx < WO) ? cbp[((size_t)gy * WO + gx) * F_ + fch] : 0.f;
        }

    constexpr int OFFT[10] = {0, 16, 32, 288, 304, 320, 576, 592, 608, 864};

    #pragma unroll 1
    for (int ts = 0; ts < nsteps; ++ts) {
        const int t = t0 + ts;
        const bf16_t* hr = (t & 1) ? h1 : h0;
        bf16_t* hw = (t & 1) ? h0 : h1;

        // ---- stage x tile: rows r0..r0+33, cols c0..c0+17 ----
        const bf16_t* xt = xb + (size_t)(bb * T_ + t) * (H_ * W_ * 8);
        for (int i = tid; i < 612; i += 512) {
            int row = i / 18, col = i % 18;
            int gy = r0 + row, gx = c0 + col;
            bf16x8 v = {};
            if (gy < H_ && gx < W_) v = *(const bf16x8*)(xt + ((size_t)gy * W_ + gx) * 8);
            *(bf16x8*)(smem + XS_OFF + row * 288 + col * 16) = v;
        }
        // ---- stage h tile (SAME pad): rows r0-1..r0+32, cols c0-1..c0+16 ----
        const bf16_t* hbR = hr + (size_t)bb * (HO * WO * F_);
        for (int i = tid; i < 2448; i += 512) {
            int pix = i >> 2, fg = i & 3;
            int row = pix / 18, col = pix % 18;
            int gy = r0 - 1 + row, gx = c0 - 1 + col;
            bf16x8 v = {};
            if (gy >= 0 && gy < HO && gx >= 0 && gx < WO)
                v = *(const bf16x8*)(hbR + ((size_t)gy * WO + gx) * F_ + fg * 8);
            *(bf16x8*)(smem + HS_OFF + fg * 9792 + row * 288 + col * 16) = v;
        }
        __syncthreads();

        f32x16 acc[2][4];
        #pragma unroll
        for (int m = 0; m < 2; ++m)
            #pragma unroll
            for (int n = 0; n < 4; ++n)
                #pragma unroll
                for (int j = 0; j < 16; ++j) acc[m][n][j] = bv[n];

        // ---- barrier-free K-loop: 23 k16-steps, 6 ds_read_b128 + 8 MFMA each ----
        #pragma unroll
        for (int kk = 0; kk < NKK; ++kk) {
            int base0;
            if (kk < 5) {
                // tap p = 2kk+half; p==9 reads past x_s (finite garbage x zero-B, in-bounds)
                base0 = baseX0 + (half ? OFFT[2 * kk + 1] : OFFT[2 * kk]);
            } else {
                const int kk2 = kk - 5, q = kk2 >> 1, fgrp = kk2 & 1;
                base0 = baseH0 + fgrp * 19584 + (q / 3) * 288 + (q % 3) * 16;
            }
            bf16x8 a0 = *(const bf16x8*)(smem + base0);
            bf16x8 a1 = *(const bf16x8*)(smem + base0 + 576);   // m=1: +2 rows
            const int bbo = kk * 4096 + l * 16;
            bf16x8 b0 = *(const bf16x8*)(smem + bbo);
            bf16x8 b1 = *(const bf16x8*)(smem + bbo + 1024);
            bf16x8 b2 = *(const bf16x8*)(smem + bbo + 2048);
            bf16x8 b3 = *(const bf16x8*)(smem + bbo + 3072);
            acc[0][0] = __builtin_amdgcn_mfma_f32_32x32x16_bf16(a0, b0, acc[0][0], 0, 0, 0);
            acc[0][1] = __builtin_amdgcn_mfma_f32_32x32x16_bf16(a0, b1, acc[0][1], 0, 0, 0);
            acc[0][2] = __builtin_amdgcn_mfma_f32_32x32x16_bf16(a0, b2, acc[0][2], 0, 0, 0);
            acc[0][3] = __builtin_amdgcn_mfma_f32_32x32x16_bf16(a0, b3, acc[0][3], 0, 0, 0);
            acc[1][0] = __builtin_amdgcn_mfma_f32_32x32x16_bf16(a1, b0, acc[1][0], 0, 0, 0);
            acc[1][1] = __builtin_amdgcn_mfma_f32_32x32x16_bf16(a1, b1, acc[1][1], 0, 0, 0);
            acc[1][2] = __builtin_amdgcn_mfma_f32_32x32x16_bf16(a1, b2, acc[1][2], 0, 0, 0);
            acc[1][3] = __builtin_amdgcn_mfma_f32_32x32x16_bf16(a1, b3, acc[1][3], 0, 0, 0);
        }

        // ---- fused LSTM epilogue: c in registers, h -> global bf16 NHWC ----
        bf16_t* hwb = hw + (size_t)bb * (HO * WO * F_);
        #pragma unroll
        for (int m = 0; m < 2; ++m)
            #pragma unroll
            for (int r = 0; r < 16; ++r) {
                const int row = (r & 3) + ((r >> 2) << 3) + (half << 2);
                const int px = w * 64 + m * 32 + row;
                const int gy = r0 + (px >> 4), gx = c0 + (px & 15);
                float zi = acc[m][0][r], zf = acc[m][1][r], zg = acc[m][2][r], zo = acc[m][3][r];
                float ig = fminf(fmaxf(0.2f * zi + 0.5f, 0.f), 1.f);
                float fg = fminf(fmaxf(0.2f * zf + 0.5f, 0.f), 1.f);
                float og = fminf(fmaxf(0.2f * zo + 0.5f, 0.f), 1.f);
                float eg = __expf(2.f * zg);
                float tg = 1.f - 2.f / (eg + 1.f);
                float cn = fg * cre[m][r] + ig * tg;
                cre[m][r] = cn;
                float ec = __expf(2.f * cn);
                float hn = og * (1.f - 2.f / (ec + 1.f));
                if (gy < HO && gx < WO)
                    hwb[((size_t)gy * WO + gx) * F_ + fch] = (bf16_t)hn;
            }

        // ---- grid barrier: relaxed polls, ONE release + ONE acquire per step ----
        if (ts < nsteps - 1) {
            __syncthreads();    // drains every wave's h stores to this XCD's L2
            if (tid == 0) {
                __threadfence();   // release: write back XCD L2 -> LLC (once)
                __hip_atomic_fetch_add(&bar[t], 1, __ATOMIC_RELAXED,
                                       __HIP_MEMORY_SCOPE_AGENT);
                int it = 0;
                // RELAXED polls: bypass L2, NO per-poll cache invalidate
                while (__hip_atomic_load(&bar[t], __ATOMIC_RELAXED,
                                         __HIP_MEMORY_SCOPE_AGENT) < NBLK &&
                       it < (1 << 14)) {
                    __builtin_amdgcn_s_sleep(2);
                    ++it;
                }
            }
            __syncthreads();
            __threadfence();       // acquire: invalidate L1/L2 once per step
        }
    }

    // ---- c state: store to global ----
    #pragma unroll
    for (int m = 0; m < 2; ++m)
        #pragma unroll
        for (int r = 0; r < 16; ++r) {
            const int row = (r & 3) + ((r >> 2) << 3) + (half << 2);
            const int px = w * 64 + m * 32 + row;
            const int gy = r0 + (px >> 4), gx = c0 + (px & 15);
            if (gy < HO && gx < WO)
                cbp[((size_t)gy * WO + gx) * F_ + fch] = cre[m][r];
        }
}

// -------- final h: NHWC bf16 -> NCHW fp32 --------
__global__ __launch_bounds__(256) void out_transpose(const bf16_t* __restrict__ h,
                                                     float* __restrict__ out) {
    __shared__ float tile[WO * 33];
    const int gy = blockIdx.x, bb = blockIdx.y;
    const bf16_t* hp = h + ((size_t)bb * HO + gy) * (WO * F_);
    for (int i = threadIdx.x; i < WO * F_; i += 256) {
        int gx = i >> 5, f = i & 31;
        tile[gx * 33 + f] = (float)hp[i];
    }
    __syncthreads();
    float* op = out + (size_t)bb * (F_ * HO * WO) + (size_t)gy * WO;
    for (int i = threadIdx.x; i < WO * F_; i += 256) {
        int f = i / WO, gx = i % WO;
        op[(size_t)f * (HO * WO) + gx] = tile[gx * 33 + f];
    }
}

extern "C" void kernel_launch(void* const* d_in, const int* in_sizes, int n_in,
                              void* d_out, int out_size, void* d_ws, size_t ws_size,
                              hipStream_t stream) {
    const float* x    = (const float*)d_in[0];
    const float* Wk   = (const float*)d_in[1];
    const float* Uk   = (const float*)d_in[2];
    const float* bias = (const float*)d_in[3];
    float* out = (float*)d_out;

    const size_t N = (size_t)B_ * HO * WO * F_;    // 4,064,256 state elems
    bf16_t* h0p  = (bf16_t*)d_ws;
    bf16_t* h1p  = h0p + N;
    bf16_t* Bp   = h1p + N;                         // 47,104 bf16
    bf16_t* xbuf = Bp + 47104;                      // 16,777,216 bf16
    float*  cbuf = (float*)(xbuf + (size_t)16777216);
    int*    bar  = (int*)(cbuf + N);                // 16 ints; total ~66.2 MB

    conv_x<<<dim3(H_, T_, B_), 128, 0, stream>>>(x, xbuf);
    prep_B<<<184, 256, 0, stream>>>(Wk, Uk, Bp);
    hipMemsetAsync(h0p, 0, N * sizeof(bf16_t), stream);
    hipMemsetAsync(cbuf, 0, N * sizeof(float), stream);
    hipMemsetAsync(bar, 0, 16 * sizeof(int), stream);

    int t0 = 0, ns = T_;
    const bf16_t* xbc = xbuf;
    const bf16_t* Bpc = Bp;
    void* args[] = {(void*)&xbc, (void*)&Bpc, (void*)&bias, (void*)&h0p,
                    (void*)&h1p, (void*)&cbuf, (void*)&bar, (void*)&t0, (void*)&ns};
    hipError_t ce = hipLaunchCooperativeKernel((const void*)lstm_persist,
                                               dim3(NBLK), dim3(512), args, 0, stream);
    if (ce != hipSuccess) {
        // fallback: 16 plain single-step launches (no in-kernel barrier runs)
        for (int t = 0; t < T_; ++t)
            lstm_persist<<<NBLK, 512, 0, stream>>>(xbuf, Bp, bias, h0p, h1p,
                                                   cbuf, bar, t, 1);
    }

    // t=15 (odd) wrote h0
    out_transpose<<<dim3(HO, B_), 256, 0, stream>>>(h0p, out);
}

// Round 6
// 715.371 us; speedup vs baseline: 2.9976x; 1.8110x over previous
//
#include <hip/hip_runtime.h>
#include <hip/hip_bf16.h>

typedef __bf16 bf16_t;
typedef __attribute__((ext_vector_type(8))) __bf16 bf16x8;
typedef __attribute__((ext_vector_type(16))) float f32x16;
typedef unsigned int u32;

#define B_ 8
#define T_ 16
#define C_ 8
#define F_ 32
#define H_ 128
#define W_ 128
#define HO 126
#define WO 126
#define NKK 23
#define NBLK 256

#define BQ (NKK * 4096)              // 94208 B: B panels, [kk][nt][lane][16B]
#define XS_OFF BQ                    // x_s [34][18][8c] bf16, row stride 288 B
#define HS_OFF (BQ + 9792)           // h_s [4fg][34][18][8f], fg stride 9792 B
#define LDS_BYTES (BQ + 9792 + 39168)   // 143168 B -> 1 block/CU

// -------- B prepack (verified R2): Bp[kk][nt][lane][j] bf16 --------
__global__ __launch_bounds__(256) void prep_B(const float* __restrict__ Wk,
                                              const float* __restrict__ Uk,
                                              bf16_t* __restrict__ Bp) {
    int e = blockIdx.x * 256 + threadIdx.x;   // grid = 23*2048 exactly
    int j = e & 7, lane = (e >> 3) & 63, nt = (e >> 9) & 3, kk = e >> 11;
    int n = nt * 32 + (lane & 31), half = lane >> 5;
    float v = 0.f;
    if (kk < 5) {
        int p = 2 * kk + half, c = j;
        if (p <= 8) v = Wk[((n * C_ + c) * 3 + p / 3) * 3 + (p % 3)];
    } else {
        int kk2 = kk - 5, q = kk2 >> 1;
        int f = ((kk2 & 1) << 4) + (half << 3) + j;
        v = Uk[((n * F_ + f) * 3 + q / 3) * 3 + (q % 3)];
    }
    Bp[e] = (bf16_t)v;
}

// -------- x: NCHW fp32 -> [b][t][y][x][8c] bf16 --------
__global__ __launch_bounds__(128) void conv_x(const float* __restrict__ x,
                                              bf16_t* __restrict__ xb) {
    const int tx = threadIdx.x;
    const int y = blockIdx.x, tb = blockIdx.y, bb = blockIdx.z;
    const float* xp = x + ((size_t)(bb * T_ + tb) * C_) * (H_ * W_) + y * W_ + tx;
    bf16x8 v;
    #pragma unroll
    for (int c = 0; c < 8; ++c) v[c] = (bf16_t)xp[(size_t)c * (H_ * W_)];
    *(bf16x8*)(xb + (((size_t)(bb * T_ + tb) * H_ + y) * W_ + tx) * 8) = v;
}

// -------- multi-step ConvLSTM; nsteps>1 requires cooperative launch --------
// Persist mode: h lives in LDS; only the 1-px halo ring crosses blocks, via
// relaxed agent-scope u32 atomics (sc1, coherent at fabric, NO cache fences).
__global__ __launch_bounds__(512, 2) void lstm_persist(
    const bf16_t* __restrict__ xb,
    const bf16_t* __restrict__ Bp,
    const float* __restrict__ bias,
    bf16_t* __restrict__ g0,    // h image, parity 0 (NHWC bf16)
    bf16_t* __restrict__ g1,    // h image, parity 1
    float* __restrict__ cbuf,   // fp32 NHWC c state (fallback round-trip)
    int* __restrict__ bar,
    int t0, int nsteps)
{
    __shared__ __align__(16) unsigned char smem[LDS_BYTES];
    const bool persist = (nsteps > 1);
    const int tid = threadIdx.x;
    const int w = tid >> 6, l = tid & 63;
    const int half = l >> 5;
    const int bid = blockIdx.x;
    const int bx = bid & 7, by = (bid >> 3) & 3, bb = bid >> 5;
    const int r0 = by * 32, c0 = bx * 16;

    // load all B panels into LDS once per dispatch
    for (int i = tid; i < BQ / 16; i += 512)
        *(bf16x8*)(smem + i * 16) = *(const bf16x8*)(Bp + i * 8);

    // persist: zero-init resident h_s (h starts at 0, halo edges stay 0)
    if (persist)
        for (int i = tid; i < 39168 / 4; i += 512)
            *(u32*)(smem + HS_OFF + i * 4) = 0u;

    const int fch = l & 31;
    float bv[4];
    #pragma unroll
    for (int n = 0; n < 4; ++n) bv[n] = bias[n * 32 + fch];

    const int trA = w * 4 + ((l & 31) >> 4);
    const int tcA = l & 15;
    const int baseX0 = XS_OFF + trA * 288 + tcA * 16;                 // m=0 (+576 m=1)
    const int baseH0 = HS_OFF + half * 9792 + trA * 288 + tcA * 16;

    // ---- c state: load from global (zeros at t0=0) ----
    float* cbp = cbuf + (size_t)bb * (HO * WO * F_);
    float cre[2][16];
    #pragma unroll
    for (int m = 0; m < 2; ++m)
        #pragma unroll
        for (int r = 0; r < 16; ++r) {
            const int crow = (r & 3) + ((r >> 2) << 3) + (half << 2);
            const int px = w * 64 + m * 32 + crow;
            const int gy = r0 + (px >> 4), gx = c0 + (px & 15);
            cre[m][r] = (gy < HO && gx < WO) ? cbp[((size_t)gy * WO + gx) * F_ + fch] : 0.f;
        }

    constexpr int OFFT[10] = {0, 16, 32, 288, 304, 320, 576, 592, 608, 864};

    #pragma unroll 1
    for (int ts = 0; ts < nsteps; ++ts) {
        const int t = t0 + ts;
        bf16_t* Gcur = (t & 1) ? g1 : g0;          // this step's publish target
        const bf16_t* Gprev = (t & 1) ? g0 : g1;   // fallback read source
        bf16_t* GcurB = Gcur + (size_t)bb * (HO * WO * F_);
        u32* GcurW = (u32*)GcurB;

        // ---- stage x tile: rows r0..r0+33, cols c0..c0+17 ----
        const bf16_t* xt = xb + (size_t)(bb * T_ + t) * (H_ * W_ * 8);
        for (int i = tid; i < 612; i += 512) {
            int row = i / 18, col = i % 18;
            int gy = r0 + row, gx = c0 + col;
            bf16x8 v = {};
            if (gy < H_ && gx < W_) v = *(const bf16x8*)(xt + ((size_t)gy * W_ + gx) * 8);
            *(bf16x8*)(smem + XS_OFF + row * 288 + col * 16) = v;
        }
        // ---- fallback only: stage full h tile (SAME pad) from Gprev ----
        if (!persist) {
            const bf16_t* hbR = Gprev + (size_t)bb * (HO * WO * F_);
            for (int i = tid; i < 2448; i += 512) {
                int pix = i >> 2, fg = i & 3;
                int row = pix / 18, col = pix % 18;
                int gy = r0 - 1 + row, gx = c0 - 1 + col;
                bf16x8 v = {};
                if (gy >= 0 && gy < HO && gx >= 0 && gx < WO)
                    v = *(const bf16x8*)(hbR + ((size_t)gy * WO + gx) * F_ + fg * 8);
                *(bf16x8*)(smem + HS_OFF + fg * 9792 + row * 288 + col * 16) = v;
            }
        }
        __syncthreads();

        f32x16 acc[2][4];
        #pragma unroll
        for (int m = 0; m < 2; ++m)
            #pragma unroll
            for (int n = 0; n < 4; ++n)
                #pragma unroll
                for (int j = 0; j < 16; ++j) acc[m][n][j] = bv[n];

        // ---- K-loop: 23 k16-steps, 6 ds_read_b128 + 8 MFMA each ----
        #pragma unroll
        for (int kk = 0; kk < NKK; ++kk) {
            int base0;
            if (kk < 5) {
                base0 = baseX0 + (half ? OFFT[2 * kk + 1] : OFFT[2 * kk]);
            } else {
                const int kk2 = kk - 5, q = kk2 >> 1, fgrp = kk2 & 1;
                base0 = baseH0 + fgrp * 19584 + (q / 3) * 288 + (q % 3) * 16;
            }
            bf16x8 a0 = *(const bf16x8*)(smem + base0);
            bf16x8 a1 = *(const bf16x8*)(smem + base0 + 576);   // m=1: +2 rows
            const int bbo = kk * 4096 + l * 16;
            bf16x8 b0 = *(const bf16x8*)(smem + bbo);
            bf16x8 b1 = *(const bf16x8*)(smem + bbo + 1024);
            bf16x8 b2 = *(const bf16x8*)(smem + bbo + 2048);
            bf16x8 b3 = *(const bf16x8*)(smem + bbo + 3072);
            acc[0][0] = __builtin_amdgcn_mfma_f32_32x32x16_bf16(a0, b0, acc[0][0], 0, 0, 0);
            acc[0][1] = __builtin_amdgcn_mfma_f32_32x32x16_bf16(a0, b1, acc[0][1], 0, 0, 0);
            acc[0][2] = __builtin_amdgcn_mfma_f32_32x32x16_bf16(a0, b2, acc[0][2], 0, 0, 0);
            acc[0][3] = __builtin_amdgcn_mfma_f32_32x32x16_bf16(a0, b3, acc[0][3], 0, 0, 0);
            acc[1][0] = __builtin_amdgcn_mfma_f32_32x32x16_bf16(a1, b0, acc[1][0], 0, 0, 0);
            acc[1][1] = __builtin_amdgcn_mfma_f32_32x32x16_bf16(a1, b1, acc[1][1], 0, 0, 0);
            acc[1][2] = __builtin_amdgcn_mfma_f32_32x32x16_bf16(a1, b2, acc[1][2], 0, 0, 0);
            acc[1][3] = __builtin_amdgcn_mfma_f32_32x32x16_bf16(a1, b3, acc[1][3], 0, 0, 0);
        }
        __syncthreads();   // all waves done reading h_s before we overwrite it

        // ---- fused LSTM epilogue ----
        const bool last = (ts == nsteps - 1);
        #pragma unroll
        for (int m = 0; m < 2; ++m)
            #pragma unroll
            for (int r = 0; r < 16; ++r) {
                const int crow = (r & 3) + ((r >> 2) << 3) + (half << 2);
                const int px = w * 64 + m * 32 + crow;
                const int prow = px >> 4, pcol = px & 15;
                const int gy = r0 + prow, gx = c0 + pcol;
                const bool valid = (gy < HO && gx < WO);
                float zi = acc[m][0][r], zf = acc[m][1][r], zg = acc[m][2][r], zo = acc[m][3][r];
                float ig = fminf(fmaxf(0.2f * zi + 0.5f, 0.f), 1.f);
                float fg = fminf(fmaxf(0.2f * zf + 0.5f, 0.f), 1.f);
                float og = fminf(fmaxf(0.2f * zo + 0.5f, 0.f), 1.f);
                float eg = __expf(2.f * zg);
                float tg = 1.f - 2.f / (eg + 1.f);
                float cn = fg * cre[m][r] + ig * tg;
                cre[m][r] = cn;
                float ec = __expf(2.f * cn);
                float hn = og * (1.f - 2.f / (ec + 1.f));
                if (persist && !last) {
                    // resident update; invalid px forced to 0 (= SAME-pad semantics)
                    *(bf16_t*)(smem + HS_OFF + (fch >> 3) * 9792 + (prow + 1) * 288 +
                               (pcol + 1) * 16 + (fch & 7) * 2) = (bf16_t)(valid ? hn : 0.f);
                }
                if ((!persist || last) && valid)
                    GcurB[((size_t)gy * WO + gx) * F_ + fch] = (bf16_t)hn;
            }

        // ---- halo exchange + grid barrier (persist, non-final steps) ----
        if (persist && ts < nsteps - 1) {
            __syncthreads();   // h_s interior updated before border reads
            // publish border ring (92 px x 16 u32) via relaxed agent atomics
            for (int i = tid; i < 1472; i += 512) {
                int pid = i >> 4, ch2 = i & 15;
                int prow, pcol;
                if (pid < 16)      { prow = 0;              pcol = pid; }
                else if (pid < 32) { prow = 31;             pcol = pid - 16; }
                else if (pid < 62) { prow = 1 + (pid - 32); pcol = 0; }
                else               { prow = 1 + (pid - 62); pcol = 15; }
                int gy = r0 + prow, gx = c0 + pcol;
                if (gy < HO && gx < WO) {
                    u32 v = *(u32*)(smem + HS_OFF + (ch2 >> 2) * 9792 + (prow + 1) * 288 +
                                    (pcol + 1) * 16 + (ch2 & 3) * 4);
                    __hip_atomic_store(&GcurW[(size_t)(gy * WO + gx) * 16 + ch2], v,
                                       __ATOMIC_RELAXED, __HIP_MEMORY_SCOPE_AGENT);
                }
            }
            __syncthreads();   // drains vmcnt: border stores at fabric before signal
            if (tid == 0) {
                __hip_atomic_fetch_add(&bar[t], 1, __ATOMIC_RELAXED,
                                       __HIP_MEMORY_SCOPE_AGENT);
                int it = 0;
                while (__hip_atomic_load(&bar[t], __ATOMIC_RELAXED,
                                         __HIP_MEMORY_SCOPE_AGENT) < NBLK &&
                       it < (1 << 14)) {
                    __builtin_amdgcn_s_sleep(2);
                    ++it;
                }
            }
            __syncthreads();
            // pull neighbor halos (100 px x 16 u32); out-of-image cells stay 0
            for (int i = tid; i < 1600; i += 512) {
                int pid = i >> 4, ch2 = i & 15;
                int prow, pcol;
                if (pid < 18)      { prow = -1;        pcol = pid - 1; }
                else if (pid < 36) { prow = 32;        pcol = pid - 19; }
                else if (pid < 68) { prow = pid - 36;  pcol = -1; }
                else               { prow = pid - 68;  pcol = 16; }
                int gy = r0 + prow, gx = c0 + pcol;
                if (gy >= 0 && gy < HO && gx >= 0 && gx < WO) {
                    u32 v = __hip_atomic_load(&GcurW[(size_t)(gy * WO + gx) * 16 + ch2],
                                              __ATOMIC_RELAXED, __HIP_MEMORY_SCOPE_AGENT);
                    *(u32*)(smem + HS_OFF + (ch2 >> 2) * 9792 + (prow + 1) * 288 +
                            (pcol + 1) * 16 + (ch2 & 3) * 4) = v;
                }
            }
            // next iteration's post-stage __syncthreads orders these ds_writes
        }
    }

    // ---- c state: store to global (fallback needs it; cheap for persist) ----
    #pragma unroll
    for (int m = 0; m < 2; ++m)
        #pragma unroll
        for (int r = 0; r < 16; ++r) {
            const int crow = (r & 3) + ((r >> 2) << 3) + (half << 2);
            const int px = w * 64 + m * 32 + crow;
            const int gy = r0 + (px >> 4), gx = c0 + (px & 15);
            if (gy < HO && gx < WO)
                cbp[((size_t)gy * WO + gx) * F_ + fch] = cre[m][r];
        }
}

// -------- final h: NHWC bf16 -> NCHW fp32 --------
__global__ __launch_bounds__(256) void out_transpose(const bf16_t* __restrict__ h,
                                                     float* __restrict__ out) {
    __shared__ float tile[WO * 33];
    const int gy = blockIdx.x, bb = blockIdx.y;
    const bf16_t* hp = h + ((size_t)bb * HO + gy) * (WO * F_);
    for (int i = threadIdx.x; i < WO * F_; i += 256) {
        int gx = i >> 5, f = i & 31;
        tile[gx * 33 + f] = (float)hp[i];
    }
    __syncthreads();
    float* op = out + (size_t)bb * (F_ * HO * WO) + (size_t)gy * WO;
    for (int i = threadIdx.x; i < WO * F_; i += 256) {
        int f = i / WO, gx = i % WO;
        op[(size_t)f * (HO * WO) + gx] = tile[gx * 33 + f];
    }
}

extern "C" void kernel_launch(void* const* d_in, const int* in_sizes, int n_in,
                              void* d_out, int out_size, void* d_ws, size_t ws_size,
                              hipStream_t stream) {
    const float* x    = (const float*)d_in[0];
    const float* Wk   = (const float*)d_in[1];
    const float* Uk   = (const float*)d_in[2];
    const float* bias = (const float*)d_in[3];
    float* out = (float*)d_out;

    const size_t N = (size_t)B_ * HO * WO * F_;    // 4,064,256 state elems
    bf16_t* g0p  = (bf16_t*)d_ws;
    bf16_t* g1p  = g0p + N;
    bf16_t* Bp   = g1p + N;                         // 47,104 bf16
    bf16_t* xbuf = Bp + 47104;                      // 16,777,216 bf16
    float*  cbuf = (float*)(xbuf + (size_t)16777216);
    int*    bar  = (int*)(cbuf + N);                // 16 ints; total ~66.2 MB

    conv_x<<<dim3(H_, T_, B_), 128, 0, stream>>>(x, xbuf);
    prep_B<<<184, 256, 0, stream>>>(Wk, Uk, Bp);
    hipMemsetAsync(g1p, 0, N * sizeof(bf16_t), stream);   // fallback t=0 source
    hipMemsetAsync(cbuf, 0, N * sizeof(float), stream);
    hipMemsetAsync(bar, 0, 16 * sizeof(int), stream);

    int t0 = 0, ns = T_;
    const bf16_t* xbc = xbuf;
    const bf16_t* Bpc = Bp;
    void* args[] = {(void*)&xbc, (void*)&Bpc, (void*)&bias, (void*)&g0p,
                    (void*)&g1p, (void*)&cbuf, (void*)&bar, (void*)&t0, (void*)&ns};
    hipError_t ce = hipLaunchCooperativeKernel((const void*)lstm_persist,
                                               dim3(NBLK), dim3(512), args, 0, stream);
    if (ce != hipSuccess) {
        // fallback: 16 plain single-step launches (no barrier executed)
        for (int t = 0; t < T_; ++t) {
            int one = 1;
            lstm_persist<<<NBLK, 512, 0, stream>>>(xbuf, Bp, bias, g0p, g1p,
                                                   cbuf, bar, t, one);
        }
    }

    // t=15 publishes full h to G[15&1] = g1 in both modes
    out_transpose<<<dim3(HO, B_), 256, 0, stream>>>(g1p, out);
}

// Round 7
// 580.961 us; speedup vs baseline: 3.6911x; 1.2314x over previous
//
#include <hip/hip_runtime.h>
#include <hip/hip_bf16.h>

typedef __bf16 bf16_t;
typedef __attribute__((ext_vector_type(8))) __bf16 bf16x8;
typedef __attribute__((ext_vector_type(16))) float f32x16;
typedef unsigned int u32;

#define B_ 8
#define T_ 16
#define C_ 8
#define F_ 32
#define H_ 128
#define W_ 128
#define HO 126
#define WO 126
#define NKK 23
#define NBLK 256

#define BQ (NKK * 4096)              // 94208 B: B panels, [kk][nt][lane][16B]
#define XS_OFF BQ                    // x_s [34][18][8c] bf16, row stride 288 B
#define HS_OFF (BQ + 9792)           // h_s [4fg][34][18][8f], fg stride 9792 B
#define LDS_BYTES (BQ + 9792 + 39168)   // 143168 B -> 1 block/CU

// -------- B prepack (verified R2): Bp[kk][nt][lane][j] bf16 --------
__global__ __launch_bounds__(256) void prep_B(const float* __restrict__ Wk,
                                              const float* __restrict__ Uk,
                                              bf16_t* __restrict__ Bp) {
    int e = blockIdx.x * 256 + threadIdx.x;   // grid = 23*2048 exactly
    int j = e & 7, lane = (e >> 3) & 63, nt = (e >> 9) & 3, kk = e >> 11;
    int n = nt * 32 + (lane & 31), half = lane >> 5;
    float v = 0.f;
    if (kk < 5) {
        int p = 2 * kk + half, c = j;
        if (p <= 8) v = Wk[((n * C_ + c) * 3 + p / 3) * 3 + (p % 3)];
    } else {
        int kk2 = kk - 5, q = kk2 >> 1;
        int f = ((kk2 & 1) << 4) + (half << 3) + j;
        v = Uk[((n * F_ + f) * 3 + q / 3) * 3 + (q % 3)];
    }
    Bp[e] = (bf16_t)v;
}

// -------- x: NCHW fp32 -> [b][t][y][x][8c] bf16 --------
__global__ __launch_bounds__(128) void conv_x(const float* __restrict__ x,
                                              bf16_t* __restrict__ xb) {
    const int tx = threadIdx.x;
    const int y = blockIdx.x, tb = blockIdx.y, bb = blockIdx.z;
    const float* xp = x + ((size_t)(bb * T_ + tb) * C_) * (H_ * W_) + y * W_ + tx;
    bf16x8 v;
    #pragma unroll
    for (int c = 0; c < 8; ++c) v[c] = (bf16_t)xp[(size_t)c * (H_ * W_)];
    *(bf16x8*)(xb + (((size_t)(bb * T_ + tb) * H_ + y) * W_ + tx) * 8) = v;
}

// -------- multi-step ConvLSTM; nsteps>1 requires cooperative launch --------
// h resident in LDS; 1-px halo crosses blocks via relaxed agent u32 atomics.
// Sync = per-block flags (128B-padded), each block waits on <=8 neighbors.
__global__ __launch_bounds__(512, 2) void lstm_persist(
    const bf16_t* __restrict__ xb,
    const bf16_t* __restrict__ Bp,
    const float* __restrict__ bias,
    bf16_t* __restrict__ g0,    // h border/image, parity 0 (NHWC bf16)
    bf16_t* __restrict__ g1,    // parity 1
    float* __restrict__ cbuf,   // fp32 NHWC c state (fallback round-trip)
    int* __restrict__ flags,    // NBLK flags, stride 32 ints (128 B)
    int t0, int nsteps)
{
    __shared__ __align__(16) unsigned char smem[LDS_BYTES];
    const bool persist = (nsteps > 1);
    const int tid = threadIdx.x;
    const int w = tid >> 6, l = tid & 63;
    const int half = l >> 5;
    const int bid = blockIdx.x;
    const int bx = bid & 7, by = (bid >> 3) & 3, bb = bid >> 5;
    const int r0 = by * 32, c0 = bx * 16;

    // load all B panels into LDS once per dispatch
    for (int i = tid; i < BQ / 16; i += 512)
        *(bf16x8*)(smem + i * 16) = *(const bf16x8*)(Bp + i * 8);

    // persist: zero-init resident h_s (h starts at 0, halo edges stay 0)
    if (persist)
        for (int i = tid; i < 39168 / 4; i += 512)
            *(u32*)(smem + HS_OFF + i * 4) = 0u;

    const int fch = l & 31;
    float bv[4];
    #pragma unroll
    for (int n = 0; n < 4; ++n) bv[n] = bias[n * 32 + fch];

    const int trA = w * 4 + ((l & 31) >> 4);
    const int tcA = l & 15;
    const int baseX0 = XS_OFF + trA * 288 + tcA * 16;                 // m=0 (+576 m=1)
    const int baseH0 = HS_OFF + half * 9792 + trA * 288 + tcA * 16;

    // ---- c state: load from global (zeros at t0=0) ----
    float* cbp = cbuf + (size_t)bb * (HO * WO * F_);
    float cre[2][16];
    #pragma unroll
    for (int m = 0; m < 2; ++m)
        #pragma unroll
        for (int r = 0; r < 16; ++r) {
            const int crow = (r & 3) + ((r >> 2) << 3) + (half << 2);
            const int px = w * 64 + m * 32 + crow;
            const int gy = r0 + (px >> 4), gx = c0 + (px & 15);
            cre[m][r] = (gy < HO && gx < WO) ? cbp[((size_t)gy * WO + gx) * F_ + fch] : 0.f;
        }

    constexpr int OFFT[10] = {0, 16, 32, 288, 304, 320, 576, 592, 608, 864};

    #pragma unroll 1
    for (int ts = 0; ts < nsteps; ++ts) {
        const int t = t0 + ts;
        bf16_t* Gcur = (t & 1) ? g1 : g0;          // this step's publish target
        const bf16_t* Gprev = (t & 1) ? g0 : g1;   // previous step's buffer
        bf16_t* GcurB = Gcur + (size_t)bb * (HO * WO * F_);
        const u32* GprevW = (const u32*)(Gprev + (size_t)bb * (HO * WO * F_));

        // ---- stage x tile: rows r0..r0+33, cols c0..c0+17 (issued pre-wait) ----
        const bf16_t* xt = xb + (size_t)(bb * T_ + t) * (H_ * W_ * 8);
        for (int i = tid; i < 612; i += 512) {
            int row = i / 18, col = i % 18;
            int gy = r0 + row, gx = c0 + col;
            bf16x8 v = {};
            if (gy < H_ && gx < W_) v = *(const bf16x8*)(xt + ((size_t)gy * W_ + gx) * 8);
            *(bf16x8*)(smem + XS_OFF + row * 288 + col * 16) = v;
        }

        // ---- fallback only: stage full h tile (SAME pad) from Gprev ----
        if (!persist) {
            const bf16_t* hbR = Gprev + (size_t)bb * (HO * WO * F_);
            for (int i = tid; i < 2448; i += 512) {
                int pix = i >> 2, fg = i & 3;
                int row = pix / 18, col = pix % 18;
                int gy = r0 - 1 + row, gx = c0 - 1 + col;
                bf16x8 v = {};
                if (gy >= 0 && gy < HO && gx >= 0 && gx < WO)
                    v = *(const bf16x8*)(hbR + ((size_t)gy * WO + gx) * F_ + fg * 8);
                *(bf16x8*)(smem + HS_OFF + fg * 9792 + row * 288 + col * 16) = v;
            }
        }

        // ---- neighbor wait: h_{t-1} borders published (flag >= t) ----
        if (persist && ts > 0 && tid == 0) {
            #pragma unroll
            for (int dy = -1; dy <= 1; ++dy)
                #pragma unroll
                for (int dx = -1; dx <= 1; ++dx) {
                    if (dx == 0 && dy == 0) continue;
                    const int nx = bx + dx, ny = by + dy;
                    if (nx < 0 || nx > 7 || ny < 0 || ny > 3) continue;
                    const int nbid = (bb << 5) | (ny << 3) | nx;
                    int it = 0;
                    while (__hip_atomic_load(&flags[nbid * 32], __ATOMIC_RELAXED,
                                             __HIP_MEMORY_SCOPE_AGENT) < t &&
                           it < (1 << 15)) {
                        __builtin_amdgcn_s_sleep(2);
                        ++it;
                    }
                }
        }
        __syncthreads();   // x-stage writes done + wait satisfied

        // ---- pull neighbor halos of h_{t-1} (100 px x 16 u32) ----
        if (persist && ts > 0) {
            for (int i = tid; i < 1600; i += 512) {
                int pid = i >> 4, ch2 = i & 15;
                int prow, pcol;
                if (pid < 18)      { prow = -1;        pcol = pid - 1; }
                else if (pid < 36) { prow = 32;        pcol = pid - 19; }
                else if (pid < 68) { prow = pid - 36;  pcol = -1; }
                else               { prow = pid - 68;  pcol = 16; }
                int gy = r0 + prow, gx = c0 + pcol;
                if (gy >= 0 && gy < HO && gx >= 0 && gx < WO) {
                    u32 v = __hip_atomic_load(&GprevW[(size_t)(gy * WO + gx) * 16 + ch2],
                                              __ATOMIC_RELAXED, __HIP_MEMORY_SCOPE_AGENT);
                    *(u32*)(smem + HS_OFF + (ch2 >> 2) * 9792 + (prow + 1) * 288 +
                            (pcol + 1) * 16 + (ch2 & 3) * 4) = v;
                }
            }
            __syncthreads();   // halo ds_writes visible before K-loop reads
        }

        f32x16 acc[2][4];
        #pragma unroll
        for (int m = 0; m < 2; ++m)
            #pragma unroll
            for (int n = 0; n < 4; ++n)
                #pragma unroll
                for (int j = 0; j < 16; ++j) acc[m][n][j] = bv[n];

        // ---- K-loop: 23 k16-steps, 6 ds_read_b128 + 8 MFMA each ----
        #pragma unroll
        for (int kk = 0; kk < NKK; ++kk) {
            int base0;
            if (kk < 5) {
                base0 = baseX0 + (half ? OFFT[2 * kk + 1] : OFFT[2 * kk]);
            } else {
                const int kk2 = kk - 5, q = kk2 >> 1, fgrp = kk2 & 1;
                base0 = baseH0 + fgrp * 19584 + (q / 3) * 288 + (q % 3) * 16;
            }
            bf16x8 a0 = *(const bf16x8*)(smem + base0);
            bf16x8 a1 = *(const bf16x8*)(smem + base0 + 576);   // m=1: +2 rows
            const int bbo = kk * 4096 + l * 16;
            bf16x8 b0 = *(const bf16x8*)(smem + bbo);
            bf16x8 b1 = *(const bf16x8*)(smem + bbo + 1024);
            bf16x8 b2 = *(const bf16x8*)(smem + bbo + 2048);
            bf16x8 b3 = *(const bf16x8*)(smem + bbo + 3072);
            acc[0][0] = __builtin_amdgcn_mfma_f32_32x32x16_bf16(a0, b0, acc[0][0], 0, 0, 0);
            acc[0][1] = __builtin_amdgcn_mfma_f32_32x32x16_bf16(a0, b1, acc[0][1], 0, 0, 0);
            acc[0][2] = __builtin_amdgcn_mfma_f32_32x32x16_bf16(a0, b2, acc[0][2], 0, 0, 0);
            acc[0][3] = __builtin_amdgcn_mfma_f32_32x32x16_bf16(a0, b3, acc[0][3], 0, 0, 0);
            acc[1][0] = __builtin_amdgcn_mfma_f32_32x32x16_bf16(a1, b0, acc[1][0], 0, 0, 0);
            acc[1][1] = __builtin_amdgcn_mfma_f32_32x32x16_bf16(a1, b1, acc[1][1], 0, 0, 0);
            acc[1][2] = __builtin_amdgcn_mfma_f32_32x32x16_bf16(a1, b2, acc[1][2], 0, 0, 0);
            acc[1][3] = __builtin_amdgcn_mfma_f32_32x32x16_bf16(a1, b3, acc[1][3], 0, 0, 0);
        }
        __syncthreads();   // all waves done reading h_s before we overwrite it

        // ---- fused LSTM epilogue ----
        const bool last = (ts == nsteps - 1);
        #pragma unroll
        for (int m = 0; m < 2; ++m)
            #pragma unroll
            for (int r = 0; r < 16; ++r) {
                const int crow = (r & 3) + ((r >> 2) << 3) + (half << 2);
                const int px = w * 64 + m * 32 + crow;
                const int prow = px >> 4, pcol = px & 15;
                const int gy = r0 + prow, gx = c0 + pcol;
                const bool valid = (gy < HO && gx < WO);
                float zi = acc[m][0][r], zf = acc[m][1][r], zg = acc[m][2][r], zo = acc[m][3][r];
                float ig = fminf(fmaxf(0.2f * zi + 0.5f, 0.f), 1.f);
                float fg = fminf(fmaxf(0.2f * zf + 0.5f, 0.f), 1.f);
                float og = fminf(fmaxf(0.2f * zo + 0.5f, 0.f), 1.f);
                float eg = __expf(2.f * zg);
                float tg = 1.f - 2.f / (eg + 1.f);
                float cn = fg * cre[m][r] + ig * tg;
                cre[m][r] = cn;
                float ec = __expf(2.f * cn);
                float hn = og * (1.f - 2.f / (ec + 1.f));
                if (persist && !last) {
                    // resident update; invalid px forced to 0 (= SAME-pad semantics)
                    *(bf16_t*)(smem + HS_OFF + (fch >> 3) * 9792 + (prow + 1) * 288 +
                               (pcol + 1) * 16 + (fch & 7) * 2) = (bf16_t)(valid ? hn : 0.f);
                }
                if ((!persist || last) && valid)
                    GcurB[((size_t)gy * WO + gx) * F_ + fch] = (bf16_t)hn;
            }

        // ---- publish border ring + raise own flag (persist, non-final) ----
        if (persist && !last) {
            __syncthreads();   // h_s border writes visible to publishing threads
            u32* GcurW = (u32*)GcurB;
            for (int i = tid; i < 1472; i += 512) {
                int pid = i >> 4, ch2 = i & 15;
                int prow, pcol;
                if (pid < 16)      { prow = 0;              pcol = pid; }
                else if (pid < 32) { prow = 31;             pcol = pid - 16; }
                else if (pid < 62) { prow = 1 + (pid - 32); pcol = 0; }
                else               { prow = 1 + (pid - 62); pcol = 15; }
                int gy = r0 + prow, gx = c0 + pcol;
                if (gy < HO && gx < WO) {
                    u32 v = *(u32*)(smem + HS_OFF + (ch2 >> 2) * 9792 + (prow + 1) * 288 +
                                    (pcol + 1) * 16 + (ch2 & 3) * 4);
                    __hip_atomic_store(&GcurW[(size_t)(gy * WO + gx) * 16 + ch2], v,
                                       __ATOMIC_RELAXED, __HIP_MEMORY_SCOPE_AGENT);
                }
            }
            __syncthreads();   // drains vmcnt: border stores at fabric before flag
            if (tid == 0)
                __hip_atomic_store(&flags[bid * 32], t + 1, __ATOMIC_RELAXED,
                                   __HIP_MEMORY_SCOPE_AGENT);
        }
    }

    // ---- c state: store to global (fallback needs it; cheap for persist) ----
    #pragma unroll
    for (int m = 0; m < 2; ++m)
        #pragma unroll
        for (int r = 0; r < 16; ++r) {
            const int crow = (r & 3) + ((r >> 2) << 3) + (half << 2);
            const int px = w * 64 + m * 32 + crow;
            const int gy = r0 + (px >> 4), gx = c0 + (px & 15);
            if (gy < HO && gx < WO)
                cbp[((size_t)gy * WO + gx) * F_ + fch] = cre[m][r];
        }
}

// -------- final h: NHWC bf16 -> NCHW fp32 --------
__global__ __launch_bounds__(256) void out_transpose(const bf16_t* __restrict__ h,
                                                     float* __restrict__ out) {
    __shared__ float tile[WO * 33];
    const int gy = blockIdx.x, bb = blockIdx.y;
    const bf16_t* hp = h + ((size_t)bb * HO + gy) * (WO * F_);
    for (int i = threadIdx.x; i < WO * F_; i += 256) {
        int gx = i >> 5, f = i & 31;
        tile[gx * 33 + f] = (float)hp[i];
    }
    __syncthreads();
    float* op = out + (size_t)bb * (F_ * HO * WO) + (size_t)gy * WO;
    for (int i = threadIdx.x; i < WO * F_; i += 256) {
        int f = i / WO, gx = i % WO;
        op[(size_t)f * (HO * WO) + gx] = tile[gx * 33 + f];
    }
}

extern "C" void kernel_launch(void* const* d_in, const int* in_sizes, int n_in,
                              void* d_out, int out_size, void* d_ws, size_t ws_size,
                              hipStream_t stream) {
    const float* x    = (const float*)d_in[0];
    const float* Wk   = (const float*)d_in[1];
    const float* Uk   = (const float*)d_in[2];
    const float* bias = (const float*)d_in[3];
    float* out = (float*)d_out;

    const size_t N = (size_t)B_ * HO * WO * F_;    // 4,064,256 state elems
    bf16_t* g0p  = (bf16_t*)d_ws;
    bf16_t* g1p  = g0p + N;
    bf16_t* Bp   = g1p + N;                         // 47,104 bf16
    bf16_t* xbuf = Bp + 47104;                      // 16,777,216 bf16
    float*  cbuf = (float*)(xbuf + (size_t)16777216);
    int*    flg  = (int*)(cbuf + N);                // 256 x 32 ints (32 KB)

    conv_x<<<dim3(H_, T_, B_), 128, 0, stream>>>(x, xbuf);
    prep_B<<<184, 256, 0, stream>>>(Wk, Uk, Bp);
    hipMemsetAsync(g1p, 0, N * sizeof(bf16_t), stream);   // fallback t=0 source
    hipMemsetAsync(cbuf, 0, N * sizeof(float), stream);
    hipMemsetAsync(flg, 0, NBLK * 32 * sizeof(int), stream);

    int t0 = 0, ns = T_;
    const bf16_t* xbc = xbuf;
    const bf16_t* Bpc = Bp;
    void* args[] = {(void*)&xbc, (void*)&Bpc, (void*)&bias, (void*)&g0p,
                    (void*)&g1p, (void*)&cbuf, (void*)&flg, (void*)&t0, (void*)&ns};
    hipError_t ce = hipLaunchCooperativeKernel((const void*)lstm_persist,
                                               dim3(NBLK), dim3(512), args, 0, stream);
    if (ce != hipSuccess) {
        // fallback: 16 plain single-step launches (no waits executed)
        for (int t = 0; t < T_; ++t) {
            int one = 1;
            lstm_persist<<<NBLK, 512, 0, stream>>>(xbuf, Bp, bias, g0p, g1p,
                                                   cbuf, flg, t, one);
        }
    }

    // t=15 publishes full h to G[15&1] = g1 in both modes
    out_transpose<<<dim3(HO, B_), 256, 0, stream>>>(g1p, out);
}